// Round 6
// baseline (1183.861 us; speedup 1.0000x reference)
//
#include <hip/hip_runtime.h>

// B=2, N=2048, K=32, H=256.  Runtime dtype detection (fp32 vs bf16).
// Round-5 post-mortem: halving barriers gained only 4.5% -> per-K-step cost is
// the compiler's s_waitcnt vmcnt(0) drain before every s_barrier (loads must
// COMPLETE each step).  Round 6: remove per-step staging entirely.  B-frags
// are read per-lane directly from the L2-resident pre-converted slots
// (pitch 32, perfectly coalesced 16B/lane); layer-1 A-frags read per-lane
// directly from global (self/nbr via per-lane E_idx, hE with inline convert).
// No sW LDS, no ds_write staging, no K-loop barriers: ~5 barriers/block
// (layer boundaries only) instead of 41.  gemm_ffn: fully LDS/barrier-free.
// LDS 74752 -> 33792 (sT only) -> 3 blocks/CU via __launch_bounds__(256,3).
//
// Scratch layout inside h_E-output region (outEb):
//   +0        Msum        fp32 [4096][256]   (4 MB)
//   +4  MB    hV1         bf16 [4096][256]   (2 MB)
//   +6  MB    Ubuf        bf16 [4096][512]   (4 MB)
//   +10 MB    dh          fp32 [4096][256]   (4 MB)
//   +14 MB    mainW slots bf16 72*8192 u16   (1.18MB) W1,W2,W3,Win,Wout
//   +16 MB    hV0         bf16 [4096][256]   (2 MB)
//   end-655360: tailW slots 40*8192 u16      W11,W12,W13 (fallback when no ws)

using u16 = unsigned short;
using bf16x8 = __attribute__((ext_vector_type(8))) short;
using f32x4  = __attribute__((ext_vector_type(4))) float;

__device__ __forceinline__ float bf2f(u16 h) {
    union { unsigned u; float f; } v; v.u = (unsigned)h << 16; return v.f;
}
__device__ __forceinline__ u16 f2bf(float f) {
    union { float f; unsigned u; } v; v.f = f;
    unsigned r = v.u + 0x7fffu + ((v.u >> 16) & 1u);
    return (u16)(r >> 16);
}
__device__ __forceinline__ float gelu_f(float x) {
    if (!(x > -10.0f)) return 0.0f;   // also catches NaN
    return 0.5f * x * (1.0f + erff(x * 0.70710678118654752f));
}
__device__ __forceinline__ u16 scrub16(u16 h) {        // bf16 NaN/Inf -> 0
    return ((h & 0x7F80u) == 0x7F80u) ? (u16)0 : h;
}
__device__ __forceinline__ float sanef(float x) {
    return (x == x && x < 1e30f && x > -1e30f) ? x : 0.0f;
}

__device__ __forceinline__ int detect_f32(const void* probe) {
    const u16* p = (const u16*)probe;
    int ok = 1;
    #pragma unroll
    for (int i = 0; i < 16; ++i) {
        int e = (p[2 * i] >> 7) & 0xFF;
        ok &= (e >= 100) & (e <= 140);
    }
    return !ok;
}
__device__ __forceinline__ int detect_i64(const void* eidx) {
    const int* p = (const int*)eidx;
    return (p[1] | p[3] | p[5] | p[7]) == 0;
}
__device__ __forceinline__ int loadidx(const void* base, int i, int i64) {
    int v = i64 ? (int)((const long long*)base)[i] : ((const int*)base)[i];
    return v & 2047;
}
__device__ __forceinline__ float loadf(const void* base, size_t i, int f32) {
    return sanef(f32 ? ((const float*)base)[i] : bf2f(((const u16*)base)[i]));
}
__device__ __forceinline__ void storef(void* base, size_t i, int f32, float v) {
    if (f32) ((float*)base)[i] = v; else ((u16*)base)[i] = f2bf(v);
}
// stage 8 consecutive elements as scrubbed bf16 (prep_k only)
__device__ __forceinline__ void stage8(const void* base, size_t idx, int f32, u16* dst) {
    u16 t[8];
    if (f32) {
        const float* p = (const float*)base + idx;
        f32x4 a = *(const f32x4*)p;
        f32x4 b = *(const f32x4*)(p + 4);
        t[0]=f2bf(sanef(a[0])); t[1]=f2bf(sanef(a[1]));
        t[2]=f2bf(sanef(a[2])); t[3]=f2bf(sanef(a[3]));
        t[4]=f2bf(sanef(b[0])); t[5]=f2bf(sanef(b[1]));
        t[6]=f2bf(sanef(b[2])); t[7]=f2bf(sanef(b[3]));
    } else {
        *(uint4*)t = *(const uint4*)((const u16*)base + idx);
        #pragma unroll
        for (int i = 0; i < 8; ++i) t[i] = scrub16(t[i]);
    }
    *(uint4*)dst = *(uint4*)t;
}

// 8-element fragment loaders
__device__ __forceinline__ bf16x8 raw8(const u16* p) { return *(const bf16x8*)p; }
__device__ __forceinline__ bf16x8 scr8(const u16* p) {
    bf16x8 r = *(const bf16x8*)p;
    #pragma unroll
    for (int i = 0; i < 8; ++i) r[i] = (short)scrub16((u16)r[i]);
    return r;
}
__device__ __forceinline__ bf16x8 cvt8(const float* p) {
    f32x4 a = *(const f32x4*)p;
    f32x4 b = *(const f32x4*)(p + 4);
    bf16x8 r;
    r[0]=(short)f2bf(sanef(a[0])); r[1]=(short)f2bf(sanef(a[1]));
    r[2]=(short)f2bf(sanef(a[2])); r[3]=(short)f2bf(sanef(a[3]));
    r[4]=(short)f2bf(sanef(b[0])); r[5]=(short)f2bf(sanef(b[1]));
    r[6]=(short)f2bf(sanef(b[2])); r[7]=(short)f2bf(sanef(b[3]));
    return r;
}

// one 32-K step of MFMAs; B fetched per-lane directly (BM: 0=slot bf16 raw,
// 1=f32 input +sanef, 2=bf16 input +scrub)
template<int BM>
__device__ __forceinline__ void mma_nb(bf16x8 a0, bf16x8 a1, const void* B,
                                       int koff, int pitch, int wn, int l15,
                                       f32x4 acc[2][8]) {
    #pragma unroll
    for (int nb = 0; nb < 8; ++nb) {
        const int colr = wn * 128 + nb * 16 + l15;
        bf16x8 b;
        if (BM == 0)      b = raw8((const u16*)B + (size_t)colr * pitch + koff);
        else if (BM == 1) b = cvt8((const float*)B + (size_t)colr * pitch + koff);
        else              b = scr8((const u16*)B + (size_t)colr * pitch + koff);
        acc[0][nb] = __builtin_amdgcn_mfma_f32_16x16x32_bf16(a0, b, acc[0][nb], 0, 0, 0);
        acc[1][nb] = __builtin_amdgcn_mfma_f32_16x16x32_bf16(a1, b, acc[1][nb], 0, 0, 0);
    }
}

// ---- prep: convert weights into unpadded slot layout + h_V into bf16 ----
__global__ __launch_bounds__(256) void prep_k(
    const void* probe, const void* hV,
    const void* W1, const void* W2, const void* W3,
    const void* Win, const void* Wout,
    const void* W11, const void* W12, const void* W13,
    void* dout, void* wsOpt)
{
    const int f32 = detect_f32(probe);
    char* outEb = (char*)dout + (size_t)1048576 * (f32 ? 4 : 2);
    const size_t eoutB = (size_t)33554432 * (f32 ? 4 : 2);
    u16* mainW = (u16*)(outEb + (14u << 20));
    u16* edgeW = wsOpt ? (u16*)wsOpt
                       : (u16*)(outEb + eoutB - (size_t)40 * 16384);
    u16* hV0   = (u16*)(outEb + (16u << 20));

    const int y  = blockIdx.y;
    const int t0 = blockIdx.x * 256 + threadIdx.x;
    const int stride = gridDim.x * 256;

    if (y < 8) {
        const void* srcs[8] = {W1, W2, W3, Win, Wout, W11, W12, W13};
        const int kd[8] = {768, 256, 256, 256, 512, 768, 256, 256};
        const int ne[8] = {196608, 65536, 65536, 131072, 131072, 196608, 65536, 65536};
        const int sb[8] = {0, 24, 32, 40, 56, 0, 24, 32};
        const void* src = srcs[y];
        u16* dstW = (y >= 5) ? edgeW : mainW;
        const int K = kd[y], n = ne[y], s0 = sb[y];
        for (int i = t0; i < n; i += stride) {
            const int row = i / K;
            const int k   = i - row * K;
            const int slot = s0 + (row >> 8) * (K >> 5) + (k >> 5);
            const u16 v = f32 ? f2bf(sanef(((const float*)src)[i]))
                              : scrub16(((const u16*)src)[i]);
            dstW[(size_t)slot * 8192 + (size_t)(row & 255) * 32 + (k & 31)] = v;
        }
    } else {
        for (int g = t0; g < 131072; g += stride) {
            u16 t[8];
            stage8(hV, (size_t)g * 8, f32, t);
            *(uint4*)(hV0 + (size_t)g * 8) = *(uint4*)t;
        }
    }
}

// Fused 3-layer message MLP, 64 edge rows/block, direct-from-L2 fragments.
// MODE 0: node message -> Msum ; MODE 1: outE = LN(hE + m3)
// SLOTS 1: B from pre-converted slots ; SLOTS 0: B from d_in (fallback tail)
template<int MODE, int SLOTS>
__global__ __launch_bounds__(256, 3) void msg_fused(
    const void* probe, const void* hVcur, const void* hE, const void* Eidx,
    const void* W1, const void* b1, const void* W2, const void* b2,
    const void* W3, const void* b3, const void* lng, const void* lnb,
    void* dout, const void* wsOpt, int blk0)
{
    __shared__ __align__(16) u16 sT[64 * 264];   // 33792 B — the only LDS

    const int f32 = detect_f32(probe);
    const int i64 = detect_i64(Eidx);
    char* outEb = (char*)dout + (size_t)1048576 * (f32 ? 4 : 2);
    const size_t eoutB = (size_t)33554432 * (f32 ? 4 : 2);
    const u16* wsl = (MODE == 0)
        ? (const u16*)(outEb + (14u << 20))
        : (wsOpt ? (const u16*)wsOpt
                 : (const u16*)(outEb + eoutB - (size_t)40 * 16384));
    const u16* hV0 = (const u16*)(outEb + (16u << 20));

    const int tid  = threadIdx.x;
    const int lane = tid & 63;
    const int wv   = tid >> 6;
    const int wm   = wv & 1;
    const int wn   = wv >> 1;
    const int l15  = lane & 15;
    const int quad = lane >> 4;
    const int m0   = (blockIdx.x + blk0) * 64;
    const int ko4  = quad * 8;

    const int row0 = wm * 32 + l15, row1 = row0 + 16;
    const int mg0  = m0 + row0,     mg1  = m0 + row1;
    const int self0 = mg0 >> 5,     self1 = mg1 >> 5;
    const int jn0 = (mg0 >> 16) * 2048 + loadidx(Eidx, mg0, i64);
    const int jn1 = (mg1 >> 16) * 2048 + loadidx(Eidx, mg1, i64);

    int col[8];
    #pragma unroll
    for (int nb = 0; nb < 8; ++nb) col[nb] = wn * 128 + nb * 16 + l15;

    const f32x4 vzero = {0.f, 0.f, 0.f, 0.f};
    f32x4 acc[2][8];
    #pragma unroll
    for (int mb = 0; mb < 2; ++mb)
        #pragma unroll
        for (int nb = 0; nb < 8; ++nb) acc[mb][nb] = vzero;

    // ---- layer 1: [hv_self | hE | hv_nbr] @ W1^T, barrier-free ----
    #pragma unroll 2
    for (int kk = 0; kk < 8; ++kk) {              // self block
        const int ko = kk * 32 + ko4;
        bf16x8 a0, a1;
        if (MODE == 0) {
            a0 = raw8(hV0 + (size_t)self0 * 256 + ko);
            a1 = raw8(hV0 + (size_t)self1 * 256 + ko);
        } else if (f32) {
            a0 = cvt8((const float*)hVcur + (size_t)self0 * 256 + ko);
            a1 = cvt8((const float*)hVcur + (size_t)self1 * 256 + ko);
        } else {
            a0 = raw8((const u16*)hVcur + (size_t)self0 * 256 + ko);
            a1 = raw8((const u16*)hVcur + (size_t)self1 * 256 + ko);
        }
        if (SLOTS)    mma_nb<0>(a0, a1, wsl + (size_t)kk * 8192, ko4, 32, wn, l15, acc);
        else if (f32) mma_nb<1>(a0, a1, W1, kk * 32 + ko4, 768, wn, l15, acc);
        else          mma_nb<2>(a0, a1, W1, kk * 32 + ko4, 768, wn, l15, acc);
    }
    #pragma unroll 2
    for (int kk = 0; kk < 8; ++kk) {              // hE block
        const int ko = kk * 32 + ko4;
        bf16x8 a0, a1;
        if (f32) {
            a0 = cvt8((const float*)hE + (size_t)mg0 * 256 + ko);
            a1 = cvt8((const float*)hE + (size_t)mg1 * 256 + ko);
        } else {
            a0 = scr8((const u16*)hE + (size_t)mg0 * 256 + ko);
            a1 = scr8((const u16*)hE + (size_t)mg1 * 256 + ko);
        }
        if (SLOTS)    mma_nb<0>(a0, a1, wsl + (size_t)(8 + kk) * 8192, ko4, 32, wn, l15, acc);
        else if (f32) mma_nb<1>(a0, a1, W1, (8 + kk) * 32 + ko4, 768, wn, l15, acc);
        else          mma_nb<2>(a0, a1, W1, (8 + kk) * 32 + ko4, 768, wn, l15, acc);
    }
    #pragma unroll 2
    for (int kk = 0; kk < 8; ++kk) {              // neighbor block
        const int ko = kk * 32 + ko4;
        bf16x8 a0, a1;
        if (MODE == 0) {
            a0 = raw8(hV0 + (size_t)jn0 * 256 + ko);
            a1 = raw8(hV0 + (size_t)jn1 * 256 + ko);
        } else if (f32) {
            a0 = cvt8((const float*)hVcur + (size_t)jn0 * 256 + ko);
            a1 = cvt8((const float*)hVcur + (size_t)jn1 * 256 + ko);
        } else {
            a0 = raw8((const u16*)hVcur + (size_t)jn0 * 256 + ko);
            a1 = raw8((const u16*)hVcur + (size_t)jn1 * 256 + ko);
        }
        if (SLOTS)    mma_nb<0>(a0, a1, wsl + (size_t)(16 + kk) * 8192, ko4, 32, wn, l15, acc);
        else if (f32) mma_nb<1>(a0, a1, W1, (16 + kk) * 32 + ko4, 768, wn, l15, acc);
        else          mma_nb<2>(a0, a1, W1, (16 + kk) * 32 + ko4, 768, wn, l15, acc);
    }
    {   // gelu -> sT
        float bv[8];
        #pragma unroll
        for (int nb = 0; nb < 8; ++nb) bv[nb] = loadf(b1, col[nb], f32);
        #pragma unroll
        for (int mb = 0; mb < 2; ++mb)
            #pragma unroll
            for (int rr = 0; rr < 4; ++rr) {
                const int row = wm * 32 + mb * 16 + quad * 4 + rr;
                #pragma unroll
                for (int nb = 0; nb < 8; ++nb)
                    sT[row * 264 + col[nb]] = f2bf(gelu_f(acc[mb][nb][rr] + bv[nb]));
            }
    }
    __syncthreads();

    // ---- layer 2 (slots 24..31), barrier-free K-loop ----
    #pragma unroll
    for (int mb = 0; mb < 2; ++mb)
        #pragma unroll
        for (int nb = 0; nb < 8; ++nb) acc[mb][nb] = vzero;
    #pragma unroll 2
    for (int kk = 0; kk < 8; ++kk) {
        const int ko = kk * 32 + ko4;
        bf16x8 a0 = raw8(sT + row0 * 264 + ko);
        bf16x8 a1 = raw8(sT + row1 * 264 + ko);
        if (SLOTS)    mma_nb<0>(a0, a1, wsl + (size_t)(24 + kk) * 8192, ko4, 32, wn, l15, acc);
        else if (f32) mma_nb<1>(a0, a1, W2, kk * 32 + ko4, 256, wn, l15, acc);
        else          mma_nb<2>(a0, a1, W2, kk * 32 + ko4, 256, wn, l15, acc);
    }
    __syncthreads();   // all reads of sT done before overwrite
    {
        float bv[8];
        #pragma unroll
        for (int nb = 0; nb < 8; ++nb) bv[nb] = loadf(b2, col[nb], f32);
        #pragma unroll
        for (int mb = 0; mb < 2; ++mb)
            #pragma unroll
            for (int rr = 0; rr < 4; ++rr) {
                const int row = wm * 32 + mb * 16 + quad * 4 + rr;
                #pragma unroll
                for (int nb = 0; nb < 8; ++nb)
                    sT[row * 264 + col[nb]] = f2bf(gelu_f(acc[mb][nb][rr] + bv[nb]));
            }
    }
    __syncthreads();

    // ---- layer 3 (slots 32..39), barrier-free K-loop ----
    #pragma unroll
    for (int mb = 0; mb < 2; ++mb)
        #pragma unroll
        for (int nb = 0; nb < 8; ++nb) acc[mb][nb] = vzero;
    #pragma unroll 2
    for (int kk = 0; kk < 8; ++kk) {
        const int ko = kk * 32 + ko4;
        bf16x8 a0 = raw8(sT + row0 * 264 + ko);
        bf16x8 a1 = raw8(sT + row1 * 264 + ko);
        if (SLOTS)    mma_nb<0>(a0, a1, wsl + (size_t)(32 + kk) * 8192, ko4, 32, wn, l15, acc);
        else if (f32) mma_nb<1>(a0, a1, W3, kk * 32 + ko4, 256, wn, l15, acc);
        else          mma_nb<2>(a0, a1, W3, kk * 32 + ko4, 256, wn, l15, acc);
    }

    if (MODE == 0) {
        float* Msum = (float*)outEb;
        const int node0 = (m0 >> 5) + wm;
        #pragma unroll
        for (int nb = 0; nb < 8; ++nb) {
            float s = acc[0][nb][0] + acc[0][nb][1] + acc[0][nb][2] + acc[0][nb][3]
                    + acc[1][nb][0] + acc[1][nb][1] + acc[1][nb][2] + acc[1][nb][3];
            s += __shfl_xor(s, 16);
            s += __shfl_xor(s, 32);
            if (quad == 0)
                Msum[(size_t)node0 * 256 + col[nb]] = s + 32.0f * loadf(b3, col[nb], f32);
        }
    } else {
        __syncthreads();            // sT reads done before sLN alias writes
        float* sLN = (float*)sT;
        float b3v[8], gv[8], bv[8];
        #pragma unroll
        for (int nb = 0; nb < 8; ++nb) {
            b3v[nb] = loadf(b3, col[nb], f32);
            gv[nb]  = loadf(lng, col[nb], f32);
            bv[nb]  = loadf(lnb, col[nb], f32);
        }
        #pragma unroll
        for (int mb = 0; mb < 2; ++mb)
            #pragma unroll
            for (int rr = 0; rr < 4; ++rr) {
                const int row = wm * 32 + mb * 16 + quad * 4 + rr;
                const size_t ebase = (size_t)(m0 + row) * 256;
                float ps = 0.f, pq = 0.f;
                #pragma unroll
                for (int nb = 0; nb < 8; ++nb) {
                    float v = acc[mb][nb][rr] + b3v[nb] + loadf(hE, ebase + col[nb], f32);
                    acc[mb][nb][rr] = v;
                    ps += v; pq += v * v;
                }
                ps += __shfl_xor(ps, 1);  pq += __shfl_xor(pq, 1);
                ps += __shfl_xor(ps, 2);  pq += __shfl_xor(pq, 2);
                ps += __shfl_xor(ps, 4);  pq += __shfl_xor(pq, 4);
                ps += __shfl_xor(ps, 8);  pq += __shfl_xor(pq, 8);
                if (l15 == 0) {
                    sLN[(wn * 64 + row) * 2]     = ps;
                    sLN[(wn * 64 + row) * 2 + 1] = pq;
                }
            }
        __syncthreads();
        #pragma unroll
        for (int mb = 0; mb < 2; ++mb)
            #pragma unroll
            for (int rr = 0; rr < 4; ++rr) {
                const int row = wm * 32 + mb * 16 + quad * 4 + rr;
                const float ts = sLN[row * 2]     + sLN[(64 + row) * 2];
                const float tq = sLN[row * 2 + 1] + sLN[(64 + row) * 2 + 1];
                const float mu   = ts * (1.0f / 256.0f);
                const float var  = fmaxf(tq * (1.0f / 256.0f) - mu * mu, 0.0f);
                const float rstd = rsqrtf(var + 1e-5f);
                const size_t obase = (size_t)(m0 + row) * 256;
                #pragma unroll
                for (int nb = 0; nb < 8; ++nb)
                    storef(outEb, obase + col[nb], f32,
                           (acc[mb][nb][rr] - mu) * rstd * gv[nb] + bv[nb]);
            }
    }
}

// FFN GEMMs over scratch, LDS-free and barrier-free.
// PHASE 0: Ubuf = gelu(hV1 @ Win^T + bin), grid (64,2).
// PHASE 1: dh = Ubuf @ Wout^T + bout, grid (64,1).
template<int PHASE>
__global__ __launch_bounds__(256, 2) void gemm_ffn(
    const void* probe, void* dout, const void* bias)
{
    const int f32 = detect_f32(probe);
    char* outEb = (char*)dout + (size_t)1048576 * (f32 ? 4 : 2);
    const u16* wsl = (const u16*)(outEb + (14u << 20));
    u16*   hV1  = (u16*)(outEb + (4u << 20));
    u16*   Ubuf = (u16*)(outEb + (6u << 20));
    float* dh   = (float*)(outEb + (10u << 20));

    const int tid  = threadIdx.x;
    const int lane = tid & 63;
    const int wv   = tid >> 6;
    const int wm   = wv & 1;
    const int wn   = wv >> 1;
    const int l15  = lane & 15;
    const int quad = lane >> 4;
    const int m0   = blockIdx.x * 64;
    const int colbase = blockIdx.y * 256;
    const int slotBase = (PHASE == 0) ? (40 + (int)blockIdx.y * 8) : 56;
    const int ko4  = quad * 8;

    const int Kdim = (PHASE == 0) ? 256 : 512;
    const u16* A   = (PHASE == 0) ? hV1 : Ubuf;
    const int lda  = (PHASE == 0) ? 256 : 512;

    const int row0 = wm * 32 + l15, row1 = row0 + 16;

    int col[8];
    #pragma unroll
    for (int nb = 0; nb < 8; ++nb) col[nb] = wn * 128 + nb * 16 + l15;

    const f32x4 vzero = {0.f, 0.f, 0.f, 0.f};
    f32x4 acc[2][8];
    #pragma unroll
    for (int mb = 0; mb < 2; ++mb)
        #pragma unroll
        for (int nb = 0; nb < 8; ++nb) acc[mb][nb] = vzero;

    #pragma unroll 2
    for (int ks = 0; ks < (Kdim >> 5); ++ks) {
        const int ko = ks * 32 + ko4;
        bf16x8 a0 = raw8(A + (size_t)(m0 + row0) * lda + ko);
        bf16x8 a1 = raw8(A + (size_t)(m0 + row1) * lda + ko);
        mma_nb<0>(a0, a1, wsl + (size_t)(slotBase + ks) * 8192, ko4, 32, wn, l15, acc);
    }

    #pragma unroll
    for (int mb = 0; mb < 2; ++mb)
        #pragma unroll
        for (int rr = 0; rr < 4; ++rr) {
            const int row = m0 + wm * 32 + mb * 16 + quad * 4 + rr;
            #pragma unroll
            for (int nb = 0; nb < 8; ++nb) {
                const int gcol = colbase + col[nb];
                const float v = acc[mb][nb][rr] + loadf(bias, gcol, f32);
                if (PHASE == 0)
                    Ubuf[(size_t)row * 512 + gcol] = f2bf(gelu_f(v));
                else
                    dh[(size_t)row * 256 + gcol] = v;
            }
        }
}

// LayerNorm rows of 256. PHASE 0: hV1 = LN(hV + Msum/16)   (scratch bf16 out)
//                        PHASE 1: outV = LN(hV1 + dh)      (adaptive out)
template<int PHASE>
__global__ __launch_bounds__(256) void ln_k(
    const void* probe, void* dout, const void* g, const void* b)
{
    const int f32 = detect_f32(probe);
    char* outEb = (char*)dout + (size_t)1048576 * (f32 ? 4 : 2);
    float* Msum = (float*)outEb;
    u16*   hV1  = (u16*)(outEb + (4u << 20));
    float* dh   = (float*)(outEb + (10u << 20));

    const int lane = threadIdx.x & 63;
    const int wvi  = threadIdx.x >> 6;
    const int row  = blockIdx.x * 4 + wvi;
    const size_t base = (size_t)row * 256 + lane * 4;

    float v[4];
    #pragma unroll
    for (int i = 0; i < 4; ++i) {
        float xb = (PHASE == 0) ? loadf(probe, base + i, f32) : bf2f(hV1[base + i]);
        float xf = (PHASE == 0) ? sanef(Msum[base + i]) * (1.0f / 16.0f)
                                : sanef(dh[base + i]);
        v[i] = xb + xf;
    }
    float s = v[0] + v[1] + v[2] + v[3];
    float q = v[0]*v[0] + v[1]*v[1] + v[2]*v[2] + v[3]*v[3];
    #pragma unroll
    for (int d = 1; d < 64; d <<= 1) { s += __shfl_xor(s, d); q += __shfl_xor(q, d); }
    const float mu   = s * (1.0f / 256.0f);
    const float var  = fmaxf(q * (1.0f / 256.0f) - mu * mu, 0.0f);
    const float rstd = rsqrtf(var + 1e-5f);

    #pragma unroll
    for (int i = 0; i < 4; ++i) {
        const float o = (v[i] - mu) * rstd * loadf(g, lane * 4 + i, f32)
                      + loadf(b, lane * 4 + i, f32);
        if (PHASE == 0) hV1[base + i] = f2bf(o);
        else            storef(dout, base + i, f32, o);
    }
}

extern "C" void kernel_launch(void* const* d_in, const int* in_sizes, int n_in,
                              void* d_out, int out_size, void* d_ws, size_t ws_size,
                              hipStream_t stream)
{
    (void)in_sizes; (void)n_in; (void)out_size;
    const void* probe = d_in[0];
    void* wsOpt = (ws_size >= (size_t)40 * 16384) ? d_ws : nullptr;

    // ---- Phase 0: pre-convert weights + h_V once ----
    prep_k<<<dim3(128, 9), 256, 0, stream>>>(
        probe, d_in[0],
        d_in[3], d_in[5], d_in[7],        // W1 W2 W3
        d_in[15], d_in[17],               // Win Wout
        d_in[9], d_in[11], d_in[13],      // W11 W12 W13
        d_out, wsOpt);

    // ---- Phase A: node message + node update ----
    msg_fused<0, 1><<<dim3(2048), 256, 0, stream>>>(
        probe, nullptr, d_in[1], d_in[2],
        nullptr, d_in[4], nullptr, d_in[6], nullptr, d_in[8],
        nullptr, nullptr, d_out, nullptr, 0);
    ln_k<0><<<dim3(1024), 256, 0, stream>>>(probe, d_out, d_in[19], d_in[20]);

    // ---- Phase B: FFN ----
    gemm_ffn<0><<<dim3(64, 2), 256, 0, stream>>>(probe, d_out, d_in[16]);
    gemm_ffn<1><<<dim3(64, 1), 256, 0, stream>>>(probe, d_out, d_in[18]);
    ln_k<1><<<dim3(1024), 256, 0, stream>>>(probe, d_out, d_in[21], d_in[22]);

    // ---- Phase C: edge message + edge update ----
    if (wsOpt) {
        // edge weight slots live in d_ws: one dispatch covers everything
        msg_fused<1, 1><<<dim3(2048), 256, 0, stream>>>(
            probe, d_out, d_in[1], d_in[2],
            nullptr, d_in[10], nullptr, d_in[12], nullptr, d_in[14],
            d_in[23], d_in[24], d_out, wsOpt, 0);
    } else {
        // fallback: slots in tail (40*16384 B) of output region.
        // safe rows (bf16 worst case): (67108864-655360)/512 = 129792 -> 2028 blocks
        msg_fused<1, 1><<<dim3(2028), 256, 0, stream>>>(
            probe, d_out, d_in[1], d_in[2],
            nullptr, d_in[10], nullptr, d_in[12], nullptr, d_in[14],
            d_in[23], d_in[24], d_out, nullptr, 0);
        msg_fused<1, 0><<<dim3(20), 256, 0, stream>>>(
            probe, d_out, d_in[1], d_in[2],
            d_in[9], d_in[10], d_in[11], d_in[12], d_in[13], d_in[14],
            d_in[23], d_in[24], d_out, nullptr, 2028);
    }
}

// Round 8
// 746.163 us; speedup vs baseline: 1.5866x; 1.5866x over previous
//
#include <hip/hip_runtime.h>

// B=2, N=2048, K=32, H=256.  Runtime dtype detection (fp32 vs bf16).
// Round-6 post-mortem: direct-from-L2 B fragments (no LDS) doubled msg time
// (8 VMEM loads/wave/K-step, no cross-wave reuse) and launch_bounds(256,3)
// re-triggered spills.  LDS weight staging is right; barriers aren't the
// limiter.  Round 7: amortize staging 4x -- 256-row M-tile per block,
// 1024 threads / 16 waves (4 waves/SIMD), per-wave code IDENTICAL to the
// verified round-5 kernel (32x128 per wave, acc[2][8], ~92 VGPR).  Weight
// bytes staged per output row /4, barrier drains /4, waves/SIMD 2->4.
// LDS = sT 256*264*2 (135168) + sW 20480 = 155648 B -> 1 block/CU.
// sA aliased into sT (live only in layer-1 K-loop).  gemm_ffn / ln_k / prep
// are exact round-5 (verified 792us) versions.
// (Round-7 bench was an infra container failure; resubmitted unchanged.)
//
// Scratch layout inside h_E-output region (outEb):
//   +0        Msum        fp32 [4096][256]   (4 MB)
//   +4  MB    hV1         bf16 [4096][256]   (2 MB)
//   +6  MB    Ubuf        bf16 [4096][512]   (4 MB)
//   +10 MB    dh          fp32 [4096][256]   (4 MB)
//   +14 MB    mainW slots bf16 72*10240 u16  (~1.4MB) W1,W2,W3,Win,Wout
//   +16 MB    hV0         bf16 [4096][256]   (2 MB)
//   end-819200: tailW slots 40*10240 u16     W11,W12,W13 (fallback when no ws)

using u16 = unsigned short;
using bf16x8 = __attribute__((ext_vector_type(8))) short;
using f32x4  = __attribute__((ext_vector_type(4))) float;

__device__ __forceinline__ float bf2f(u16 h) {
    union { unsigned u; float f; } v; v.u = (unsigned)h << 16; return v.f;
}
__device__ __forceinline__ u16 f2bf(float f) {
    union { float f; unsigned u; } v; v.f = f;
    unsigned r = v.u + 0x7fffu + ((v.u >> 16) & 1u);
    return (u16)(r >> 16);
}
__device__ __forceinline__ float gelu_f(float x) {
    if (!(x > -10.0f)) return 0.0f;   // also catches NaN
    return 0.5f * x * (1.0f + erff(x * 0.70710678118654752f));
}
__device__ __forceinline__ u16 scrub16(u16 h) {        // bf16 NaN/Inf -> 0
    return ((h & 0x7F80u) == 0x7F80u) ? (u16)0 : h;
}
__device__ __forceinline__ float sanef(float x) {
    return (x == x && x < 1e30f && x > -1e30f) ? x : 0.0f;
}

__device__ __forceinline__ int detect_f32(const void* probe) {
    const u16* p = (const u16*)probe;
    int ok = 1;
    #pragma unroll
    for (int i = 0; i < 16; ++i) {
        int e = (p[2 * i] >> 7) & 0xFF;
        ok &= (e >= 100) & (e <= 140);
    }
    return !ok;
}
__device__ __forceinline__ int detect_i64(const void* eidx) {
    const int* p = (const int*)eidx;
    return (p[1] | p[3] | p[5] | p[7]) == 0;
}
__device__ __forceinline__ int loadidx(const void* base, int i, int i64) {
    int v = i64 ? (int)((const long long*)base)[i] : ((const int*)base)[i];
    return v & 2047;
}
__device__ __forceinline__ float loadf(const void* base, size_t i, int f32) {
    return sanef(f32 ? ((const float*)base)[i] : bf2f(((const u16*)base)[i]));
}
__device__ __forceinline__ void storef(void* base, size_t i, int f32, float v) {
    if (f32) ((float*)base)[i] = v; else ((u16*)base)[i] = f2bf(v);
}
// stage 8 consecutive elements (idx multiple of 8) as scrubbed bf16 into LDS
__device__ __forceinline__ void stage8(const void* base, size_t idx, int f32, u16* dst) {
    u16 t[8];
    if (f32) {
        const float* p = (const float*)base + idx;
        f32x4 a = *(const f32x4*)p;
        f32x4 b = *(const f32x4*)(p + 4);
        t[0]=f2bf(sanef(a[0])); t[1]=f2bf(sanef(a[1]));
        t[2]=f2bf(sanef(a[2])); t[3]=f2bf(sanef(a[3]));
        t[4]=f2bf(sanef(b[0])); t[5]=f2bf(sanef(b[1]));
        t[6]=f2bf(sanef(b[2])); t[7]=f2bf(sanef(b[3]));
    } else {
        *(uint4*)t = *(const uint4*)((const u16*)base + idx);
        #pragma unroll
        for (int i = 0; i < 8; ++i) t[i] = scrub16(t[i]);
    }
    *(uint4*)dst = *(uint4*)t;
}
// convert-staging of one 256x32 weight slice, 1024 threads (SLOTS=0 fallback)
__device__ __forceinline__ void stage_w2(const void* B, int ldb, int k0,
                                         int f32, u16* sW, int tid) {
    const int rr = tid >> 2, cc = tid & 3;
    stage8(B, (size_t)rr * ldb + k0 + cc * 8, f32, sW + rr * 40 + cc * 8);
}
// raw copy of one pre-converted slot (20480 B = 1280 uint4), 1024 threads
__device__ __forceinline__ void stage_w_copy2(const u16* wsrc, u16* sW, int tid) {
    const uint4* s = (const uint4*)wsrc;
    uint4* d = (uint4*)sW;
    d[tid] = s[tid];
    if (tid < 256) d[1024 + tid] = s[1024 + tid];
}
// raw slot copy, 256 threads (gemm_ffn, unchanged from round 5)
__device__ __forceinline__ void stage_w_copy(const u16* wsrc, u16* sW, int tid) {
    const uint4* s = (const uint4*)wsrc;
    uint4* d = (uint4*)sW;
    #pragma unroll
    for (int i = 0; i < 5; ++i) d[tid + i * 256] = s[tid + i * 256];
}

// one K-step of MFMAs: wave (wm,wn) covers rows wm*32..+32, cols wn*128..+128
__device__ __forceinline__ void mma_tiles(const u16* aBase, int aStride, int aOff,
                                          const u16* sW, int wm, int wn, int l15, int quad,
                                          f32x4 acc[2][8]) {
    bf16x8 a0 = *(const bf16x8*)(aBase + (wm * 32 + l15) * aStride + aOff + quad * 8);
    bf16x8 a1 = *(const bf16x8*)(aBase + (wm * 32 + 16 + l15) * aStride + aOff + quad * 8);
    #pragma unroll
    for (int nb = 0; nb < 8; ++nb) {
        bf16x8 bfr = *(const bf16x8*)(sW + (wn * 128 + nb * 16 + l15) * 40 + quad * 8);
        acc[0][nb] = __builtin_amdgcn_mfma_f32_16x16x32_bf16(a0, bfr, acc[0][nb], 0, 0, 0);
        acc[1][nb] = __builtin_amdgcn_mfma_f32_16x16x32_bf16(a1, bfr, acc[1][nb], 0, 0, 0);
    }
}

// ---- prep: convert weights into slot layout + h_V into bf16 scratch ----
__global__ __launch_bounds__(256) void prep_k(
    const void* probe, const void* hV,
    const void* W1, const void* W2, const void* W3,
    const void* Win, const void* Wout,
    const void* W11, const void* W12, const void* W13,
    void* dout, void* wsOpt)
{
    const int f32 = detect_f32(probe);
    char* outEb = (char*)dout + (size_t)1048576 * (f32 ? 4 : 2);
    const size_t eoutB = (size_t)33554432 * (f32 ? 4 : 2);
    u16* mainW = (u16*)(outEb + (14u << 20));
    u16* edgeW = wsOpt ? (u16*)wsOpt
                       : (u16*)(outEb + eoutB - (size_t)40 * 20480);
    u16* hV0   = (u16*)(outEb + (16u << 20));

    const int y  = blockIdx.y;
    const int t0 = blockIdx.x * 256 + threadIdx.x;
    const int stride = gridDim.x * 256;

    if (y < 8) {
        const void* srcs[8] = {W1, W2, W3, Win, Wout, W11, W12, W13};
        const int kd[8] = {768, 256, 256, 256, 512, 768, 256, 256};
        const int ne[8] = {196608, 65536, 65536, 131072, 131072, 196608, 65536, 65536};
        const int sb[8] = {0, 24, 32, 40, 56, 0, 24, 32};
        const void* src = srcs[y];
        u16* dstW = (y >= 5) ? edgeW : mainW;
        const int K = kd[y], n = ne[y], s0 = sb[y];
        for (int i = t0; i < n; i += stride) {
            const int row = i / K;
            const int k   = i - row * K;
            const int slot = s0 + (row >> 8) * (K >> 5) + (k >> 5);
            const u16 v = f32 ? f2bf(sanef(((const float*)src)[i]))
                              : scrub16(((const u16*)src)[i]);
            dstW[(size_t)slot * 10240 + (size_t)(row & 255) * 40 + (k & 31)] = v;
        }
    } else {
        for (int g = t0; g < 131072; g += stride) {
            u16 t[8];
            stage8(hV, (size_t)g * 8, f32, t);
            *(uint4*)(hV0 + (size_t)g * 8) = *(uint4*)t;
        }
    }
}

// Fused 3-layer message MLP, 256 edge rows/block, 1024 threads / 16 waves.
// MODE 0: node message -> Msum ; MODE 1: outE = LN(hE + m3)
// SLOTS 1: weights from pre-converted slots ; SLOTS 0: convert from d_in
template<int MODE, int SLOTS>
__global__ __launch_bounds__(1024, 4) void msg_fused(
    const void* probe, const void* hVcur, const void* hE, const void* Eidx,
    const void* W1, const void* b1, const void* W2, const void* b2,
    const void* W3, const void* b3, const void* lng, const void* lnb,
    void* dout, const void* wsOpt, int blk0)
{
    __shared__ __align__(16) u16 sT[256 * 264];   // 135168 B
    __shared__ __align__(16) u16 sW[256 * 40];    // 20480 B
    u16* sA = sT;   // [256][40] alias: live only in layer-1 K-loop

    const int f32 = detect_f32(probe);
    const int i64 = detect_i64(Eidx);
    char* outEb = (char*)dout + (size_t)1048576 * (f32 ? 4 : 2);
    const size_t eoutB = (size_t)33554432 * (f32 ? 4 : 2);
    const u16* wsl = (MODE == 0)
        ? (const u16*)(outEb + (14u << 20))
        : (wsOpt ? (const u16*)wsOpt
                 : (const u16*)(outEb + eoutB - (size_t)40 * 20480));
    const u16* hV0 = (const u16*)(outEb + (16u << 20));

    const int tid  = threadIdx.x;
    const int lane = tid & 63;
    const int wv   = tid >> 6;     // 0..15
    const int wm   = wv >> 1;      // 0..7   (32-row group)
    const int wn   = wv & 1;       // 0..1   (128-col half)
    const int l15  = lane & 15;
    const int quad = lane >> 4;
    const int m0   = (blockIdx.x + blk0) * 256;

    const int r = tid >> 2, c = tid & 3;       // staging: row 0..255, chunk 0..3
    const int mg_r   = m0 + r;
    const int node_r = mg_r >> 5;
    const int bidx_r = mg_r >> 16;
    const int jn_r   = bidx_r * 2048 + loadidx(Eidx, mg_r, i64);
    const size_t selfOff = (size_t)node_r * 256;
    const size_t eOff    = (size_t)mg_r   * 256;
    const size_t nbrOff  = (size_t)jn_r   * 256;

    int col[8];
    #pragma unroll
    for (int nb = 0; nb < 8; ++nb) col[nb] = wn * 128 + nb * 16 + l15;

    const f32x4 vzero = {0.f, 0.f, 0.f, 0.f};
    f32x4 acc[2][8];
    #pragma unroll
    for (int mb = 0; mb < 2; ++mb)
        #pragma unroll
        for (int nb = 0; nb < 8; ++nb) acc[mb][nb] = vzero;

    // layer-1 A-tile stager, ks = 0..23 (each thread stages 8 elems of 256x32)
    auto stageA = [&](int ks) {
        u16* d = sA + r * 40 + c * 8;
        if (ks < 8 || ks >= 16) {
            const size_t aoff = ((ks < 8) ? selfOff : nbrOff)
                              + (size_t)(ks & 7) * 32 + (size_t)c * 8;
            if (MODE == 0) *(uint4*)d = *(const uint4*)(hV0 + aoff);  // clean bf16
            else           stage8(hVcur, aoff, f32, d);               // dtype convert
        } else {
            stage8(hE, eOff + (size_t)(ks & 7) * 32 + (size_t)c * 8, f32, d);
        }
    };

    // ---- layer 1: gelu([hv_self | hE | hv_nbr] @ W1^T + b1) -> sT ----
    for (int ks = 0; ks < 24; ++ks) {
        if (SLOTS) stage_w_copy2(wsl + (size_t)ks * 10240, sW, tid);
        else       stage_w2(W1, 768, ks * 32, f32, sW, tid);
        stageA(ks);
        __syncthreads();
        mma_tiles(sA, 40, 0, sW, wm, wn, l15, quad, acc);
        __syncthreads();
    }
    {
        float bv[8];
        #pragma unroll
        for (int nb = 0; nb < 8; ++nb) bv[nb] = loadf(b1, col[nb], f32);
        #pragma unroll
        for (int mb = 0; mb < 2; ++mb)
            #pragma unroll
            for (int rr = 0; rr < 4; ++rr) {
                const int row = wm * 32 + mb * 16 + quad * 4 + rr;
                #pragma unroll
                for (int nb = 0; nb < 8; ++nb)
                    sT[row * 264 + col[nb]] = f2bf(gelu_f(acc[mb][nb][rr] + bv[nb]));
            }
    }
    __syncthreads();

    // ---- layer 2 (slots 24..31) ----
    #pragma unroll
    for (int mb = 0; mb < 2; ++mb)
        #pragma unroll
        for (int nb = 0; nb < 8; ++nb) acc[mb][nb] = vzero;
    for (int ks = 0; ks < 8; ++ks) {
        if (SLOTS) stage_w_copy2(wsl + (size_t)(24 + ks) * 10240, sW, tid);
        else       stage_w2(W2, 256, ks * 32, f32, sW, tid);
        __syncthreads();
        mma_tiles(sT, 264, ks * 32, sW, wm, wn, l15, quad, acc);
        __syncthreads();
    }
    {
        float bv[8];
        #pragma unroll
        for (int nb = 0; nb < 8; ++nb) bv[nb] = loadf(b2, col[nb], f32);
        #pragma unroll
        for (int mb = 0; mb < 2; ++mb)
            #pragma unroll
            for (int rr = 0; rr < 4; ++rr) {
                const int row = wm * 32 + mb * 16 + quad * 4 + rr;
                #pragma unroll
                for (int nb = 0; nb < 8; ++nb)
                    sT[row * 264 + col[nb]] = f2bf(gelu_f(acc[mb][nb][rr] + bv[nb]));
            }
    }
    __syncthreads();

    // ---- layer 3 (slots 32..39) ----
    #pragma unroll
    for (int mb = 0; mb < 2; ++mb)
        #pragma unroll
        for (int nb = 0; nb < 8; ++nb) acc[mb][nb] = vzero;
    for (int ks = 0; ks < 8; ++ks) {
        if (SLOTS) stage_w_copy2(wsl + (size_t)(32 + ks) * 10240, sW, tid);
        else       stage_w2(W3, 256, ks * 32, f32, sW, tid);
        __syncthreads();
        mma_tiles(sT, 264, ks * 32, sW, wm, wn, l15, quad, acc);
        __syncthreads();
    }

    if (MODE == 0) {
        float* Msum = (float*)outEb;
        const int node0 = (m0 >> 5) + wm;     // block covers 8 nodes, one per wm
        #pragma unroll
        for (int nb = 0; nb < 8; ++nb) {
            float s = acc[0][nb][0] + acc[0][nb][1] + acc[0][nb][2] + acc[0][nb][3]
                    + acc[1][nb][0] + acc[1][nb][1] + acc[1][nb][2] + acc[1][nb][3];
            s += __shfl_xor(s, 16);
            s += __shfl_xor(s, 32);
            if (quad == 0)
                Msum[(size_t)node0 * 256 + col[nb]] = s + 32.0f * loadf(b3, col[nb], f32);
        }
    } else {
        float* sLN = (float*)sT;    // sT reads done (barrier above); reuse
        float b3v[8], gv[8], bv[8];
        #pragma unroll
        for (int nb = 0; nb < 8; ++nb) {
            b3v[nb] = loadf(b3, col[nb], f32);
            gv[nb]  = loadf(lng, col[nb], f32);
            bv[nb]  = loadf(lnb, col[nb], f32);
        }
        #pragma unroll
        for (int mb = 0; mb < 2; ++mb)
            #pragma unroll
            for (int rr = 0; rr < 4; ++rr) {
                const int row = wm * 32 + mb * 16 + quad * 4 + rr;
                const size_t ebase = (size_t)(m0 + row) * 256;
                float ps = 0.f, pq = 0.f;
                #pragma unroll
                for (int nb = 0; nb < 8; ++nb) {
                    float v = acc[mb][nb][rr] + b3v[nb] + loadf(hE, ebase + col[nb], f32);
                    acc[mb][nb][rr] = v;
                    ps += v; pq += v * v;
                }
                ps += __shfl_xor(ps, 1);  pq += __shfl_xor(pq, 1);
                ps += __shfl_xor(ps, 2);  pq += __shfl_xor(pq, 2);
                ps += __shfl_xor(ps, 4);  pq += __shfl_xor(pq, 4);
                ps += __shfl_xor(ps, 8);  pq += __shfl_xor(pq, 8);
                if (l15 == 0) {
                    sLN[(wn * 256 + row) * 2]     = ps;
                    sLN[(wn * 256 + row) * 2 + 1] = pq;
                }
            }
        __syncthreads();
        #pragma unroll
        for (int mb = 0; mb < 2; ++mb)
            #pragma unroll
            for (int rr = 0; rr < 4; ++rr) {
                const int row = wm * 32 + mb * 16 + quad * 4 + rr;
                const float ts = sLN[row * 2]     + sLN[(256 + row) * 2];
                const float tq = sLN[row * 2 + 1] + sLN[(256 + row) * 2 + 1];
                const float mu   = ts * (1.0f / 256.0f);
                const float var  = fmaxf(tq * (1.0f / 256.0f) - mu * mu, 0.0f);
                const float rstd = rsqrtf(var + 1e-5f);
                const size_t obase = (size_t)(m0 + row) * 256;
                #pragma unroll
                for (int nb = 0; nb < 8; ++nb)
                    storef(outEb, obase + col[nb], f32,
                           (acc[mb][nb][rr] - mu) * rstd * gv[nb] + bv[nb]);
            }
    }
}

// FFN GEMMs over scratch (exact round-5 version).
// PHASE 0: Ubuf = gelu(hV1 @ Win^T + bin), grid (64,2).
// PHASE 1: dh = Ubuf @ Wout^T + bout, grid (64,1).
template<int PHASE>
__global__ __launch_bounds__(256, 2) void gemm_ffn(
    const void* probe, void* dout, const void* bias)
{
    __shared__ __align__(16) u16 sW[256 * 40];
    __shared__ __align__(16) u16 sA[64 * 40];

    const int f32 = detect_f32(probe);
    char* outEb = (char*)dout + (size_t)1048576 * (f32 ? 4 : 2);
    const u16* wsl = (const u16*)(outEb + (14u << 20));
    u16*   hV1  = (u16*)(outEb + (4u << 20));
    u16*   Ubuf = (u16*)(outEb + (6u << 20));
    float* dh   = (float*)(outEb + (10u << 20));

    const int tid  = threadIdx.x;
    const int lane = tid & 63;
    const int wv   = tid >> 6;
    const int wm   = wv & 1;
    const int wn   = wv >> 1;
    const int l15  = lane & 15;
    const int quad = lane >> 4;
    const int m0   = blockIdx.x * 64;
    const int colbase = blockIdx.y * 256;
    const int slotBase = (PHASE == 0) ? (40 + (int)blockIdx.y * 8) : 56;

    const int Kdim = (PHASE == 0) ? 256 : 512;
    const u16* A   = (PHASE == 0) ? hV1 : Ubuf;
    const int lda  = (PHASE == 0) ? 256 : 512;

    int col[8];
    #pragma unroll
    for (int nb = 0; nb < 8; ++nb) col[nb] = wn * 128 + nb * 16 + l15;

    const f32x4 vzero = {0.f, 0.f, 0.f, 0.f};
    f32x4 acc[2][8];
    #pragma unroll
    for (int mb = 0; mb < 2; ++mb)
        #pragma unroll
        for (int nb = 0; nb < 8; ++nb) acc[mb][nb] = vzero;

    const int r = tid >> 2, c = tid & 3;
    for (int ks = 0; ks < (Kdim >> 5); ++ks) {
        const int k0 = ks * 32;
        stage_w_copy(wsl + (size_t)(slotBase + ks) * 10240, sW, tid);
        *(uint4*)(sA + r * 40 + c * 8) =
            *(const uint4*)(A + (size_t)(m0 + r) * lda + k0 + c * 8);
        __syncthreads();
        mma_tiles(sA, 40, 0, sW, wm, wn, l15, quad, acc);
        __syncthreads();
    }

    #pragma unroll
    for (int mb = 0; mb < 2; ++mb)
        #pragma unroll
        for (int rr = 0; rr < 4; ++rr) {
            const int row = m0 + wm * 32 + mb * 16 + quad * 4 + rr;
            #pragma unroll
            for (int nb = 0; nb < 8; ++nb) {
                const int gcol = colbase + col[nb];
                const float v = acc[mb][nb][rr] + loadf(bias, gcol, f32);
                if (PHASE == 0)
                    Ubuf[(size_t)row * 512 + gcol] = f2bf(gelu_f(v));
                else
                    dh[(size_t)row * 256 + gcol] = v;
            }
        }
}

// LayerNorm rows of 256. PHASE 0: hV1 = LN(hV + Msum/16)   (scratch bf16 out)
//                        PHASE 1: outV = LN(hV1 + dh)      (adaptive out)
template<int PHASE>
__global__ __launch_bounds__(256) void ln_k(
    const void* probe, void* dout, const void* g, const void* b)
{
    const int f32 = detect_f32(probe);
    char* outEb = (char*)dout + (size_t)1048576 * (f32 ? 4 : 2);
    float* Msum = (float*)outEb;
    u16*   hV1  = (u16*)(outEb + (4u << 20));
    float* dh   = (float*)(outEb + (10u << 20));

    const int lane = threadIdx.x & 63;
    const int wvi  = threadIdx.x >> 6;
    const int row  = blockIdx.x * 4 + wvi;
    const size_t base = (size_t)row * 256 + lane * 4;

    float v[4];
    #pragma unroll
    for (int i = 0; i < 4; ++i) {
        float xb = (PHASE == 0) ? loadf(probe, base + i, f32) : bf2f(hV1[base + i]);
        float xf = (PHASE == 0) ? sanef(Msum[base + i]) * (1.0f / 16.0f)
                                : sanef(dh[base + i]);
        v[i] = xb + xf;
    }
    float s = v[0] + v[1] + v[2] + v[3];
    float q = v[0]*v[0] + v[1]*v[1] + v[2]*v[2] + v[3]*v[3];
    #pragma unroll
    for (int d = 1; d < 64; d <<= 1) { s += __shfl_xor(s, d); q += __shfl_xor(q, d); }
    const float mu   = s * (1.0f / 256.0f);
    const float var  = fmaxf(q * (1.0f / 256.0f) - mu * mu, 0.0f);
    const float rstd = rsqrtf(var + 1e-5f);

    #pragma unroll
    for (int i = 0; i < 4; ++i) {
        const float o = (v[i] - mu) * rstd * loadf(g, lane * 4 + i, f32)
                      + loadf(b, lane * 4 + i, f32);
        if (PHASE == 0) hV1[base + i] = f2bf(o);
        else            storef(dout, base + i, f32, o);
    }
}

extern "C" void kernel_launch(void* const* d_in, const int* in_sizes, int n_in,
                              void* d_out, int out_size, void* d_ws, size_t ws_size,
                              hipStream_t stream)
{
    (void)in_sizes; (void)n_in; (void)out_size;
    const void* probe = d_in[0];
    void* wsOpt = (ws_size >= (size_t)40 * 20480) ? d_ws : nullptr;

    // ---- Phase 0: pre-convert weights + h_V once ----
    prep_k<<<dim3(128, 9), 256, 0, stream>>>(
        probe, d_in[0],
        d_in[3], d_in[5], d_in[7],        // W1 W2 W3
        d_in[15], d_in[17],               // Win Wout
        d_in[9], d_in[11], d_in[13],      // W11 W12 W13
        d_out, wsOpt);

    // ---- Phase A: node message + node update ----
    msg_fused<0, 1><<<dim3(512), 1024, 0, stream>>>(
        probe, nullptr, d_in[1], d_in[2],
        nullptr, d_in[4], nullptr, d_in[6], nullptr, d_in[8],
        nullptr, nullptr, d_out, nullptr, 0);
    ln_k<0><<<dim3(1024), 256, 0, stream>>>(probe, d_out, d_in[19], d_in[20]);

    // ---- Phase B: FFN ----
    gemm_ffn<0><<<dim3(64, 2), 256, 0, stream>>>(probe, d_out, d_in[16]);
    gemm_ffn<1><<<dim3(64, 1), 256, 0, stream>>>(probe, d_out, d_in[18]);
    ln_k<1><<<dim3(1024), 256, 0, stream>>>(probe, d_out, d_in[21], d_in[22]);

    // ---- Phase C: edge message + edge update ----
    if (wsOpt) {
        // edge weight slots live in d_ws: one dispatch covers everything
        msg_fused<1, 1><<<dim3(512), 1024, 0, stream>>>(
            probe, d_out, d_in[1], d_in[2],
            nullptr, d_in[10], nullptr, d_in[12], nullptr, d_in[14],
            d_in[23], d_in[24], d_out, wsOpt, 0);
    } else {
        // fallback: slots in tail (819200 B) of output region.
        // bf16 worst case: safe rows < 129472 -> 505 blocks * 256 = 129280.
        msg_fused<1, 1><<<dim3(505), 1024, 0, stream>>>(
            probe, d_out, d_in[1], d_in[2],
            nullptr, d_in[10], nullptr, d_in[12], nullptr, d_in[14],
            d_in[23], d_in[24], d_out, nullptr, 0);
        msg_fused<1, 0><<<dim3(7), 1024, 0, stream>>>(
            probe, d_out, d_in[1], d_in[2],
            d_in[9], d_in[10], d_in[11], d_in[12], d_in[13], d_in[14],
            d_in[23], d_in[24], d_out, nullptr, 505);
    }
}